// Round 2
// baseline (523.312 us; speedup 1.0000x reference)
//
#include <hip/hip_runtime.h>
#include <math.h>

#define N_NODES 100000
#define C 256
#define NB 64
#define H1D 128
#define NG 128
#define GS 257            // gsums row stride: 256 channels + 1 count
#define BLKN 32
#define BN_EPS 1e-5f

// ws layout (float offsets)
#define OFF_GSUMS 0
#define OFF_BNSUM (NG * GS)              // 32896
#define OFF_BNSQ  (OFF_BNSUM + 256)      // 33152
#define ZERO_FLOATS (OFF_BNSQ + 256)     // 33408 floats zeroed each launch
#define OFF_HMEAN ZERO_FLOATS            // 33408
#define OFF_ANG   (OFF_HMEAN + NG * C)   // 66176

// ---------------------------------------------------------------------------
// K1: per 32-node tile: h1=gelu(x@W1+b1); ang=tanh(h1@W2+b2); store ang;
//     rotate fibers by R(ang); segment-reduce rotated x into per-graph sums.
// ---------------------------------------------------------------------------
__global__ __launch_bounds__(256, 2)
void k1_angles_rot_pool(const float* __restrict__ x,
                        const int* __restrict__ batch,
                        const float* __restrict__ W1, const float* __restrict__ b1,
                        const float* __restrict__ W2, const float* __restrict__ b2,
                        float* __restrict__ gsums, float* __restrict__ ang_out)
{
    __shared__ float xs[BLKN][C];        // 32 KB
    __shared__ float wt[32 * 128];       // 16 KB staging for W1/W2 chunks
    __shared__ float h1s[BLKN][H1D];     // 16 KB
    __shared__ float csc[BLKN][NB];      // 8 KB
    __shared__ float css[BLKN][NB];      // 8 KB

    const int t = threadIdx.x;
    const int n0 = blockIdx.x * BLKN;    // N divisible by 32 (3125 blocks)

    // ---- Phase A: load x tile ----
    {
        const float4* xg = (const float4*)(x + (size_t)n0 * C);
        float4* xl = (float4*)&xs[0][0];
        #pragma unroll
        for (int m = 0; m < 8; ++m) xl[t + m * 256] = xg[t + m * 256];
    }

    // ---- Phase B: h1 = gelu(x @ W1 + b1), register tile 4 rows x 4 cols ----
    const int tx = t & 31;               // cols tx*4..tx*4+3 (128 cols)
    const int ty = t >> 5;               // rows ty*4..ty*4+3 (32 rows)
    float acc[4][4];
    #pragma unroll
    for (int i = 0; i < 4; ++i)
        #pragma unroll
        for (int j = 0; j < 4; ++j) acc[i][j] = 0.f;

    for (int kc = 0; kc < 8; ++kc) {
        __syncthreads();
        const float4* wg = (const float4*)(W1 + kc * 32 * H1D);
        float4* wl = (float4*)wt;
        #pragma unroll
        for (int m = 0; m < 4; ++m) wl[t + m * 256] = wg[t + m * 256];
        __syncthreads();
        #pragma unroll
        for (int kk = 0; kk < 32; kk += 4) {
            float4 xa[4], wb[4];
            #pragma unroll
            for (int i = 0; i < 4; ++i)
                xa[i] = *(const float4*)&xs[ty * 4 + i][kc * 32 + kk];
            #pragma unroll
            for (int m = 0; m < 4; ++m)
                wb[m] = *(const float4*)&wt[(kk + m) * 128 + tx * 4];
            #pragma unroll
            for (int i = 0; i < 4; ++i) {
                acc[i][0] += xa[i].x * wb[0].x + xa[i].y * wb[1].x + xa[i].z * wb[2].x + xa[i].w * wb[3].x;
                acc[i][1] += xa[i].x * wb[0].y + xa[i].y * wb[1].y + xa[i].z * wb[2].y + xa[i].w * wb[3].y;
                acc[i][2] += xa[i].x * wb[0].z + xa[i].y * wb[1].z + xa[i].z * wb[2].z + xa[i].w * wb[3].z;
                acc[i][3] += xa[i].x * wb[0].w + xa[i].y * wb[1].w + xa[i].z * wb[2].w + xa[i].w * wb[3].w;
            }
        }
    }
    {
        const float bb0 = b1[tx * 4 + 0], bb1 = b1[tx * 4 + 1];
        const float bb2 = b1[tx * 4 + 2], bb3 = b1[tx * 4 + 3];
        #pragma unroll
        for (int i = 0; i < 4; ++i) {
            float v0 = acc[i][0] + bb0, v1 = acc[i][1] + bb1;
            float v2 = acc[i][2] + bb2, v3 = acc[i][3] + bb3;
            v0 = 0.5f * v0 * (1.0f + erff(v0 * 0.70710678118654752f));
            v1 = 0.5f * v1 * (1.0f + erff(v1 * 0.70710678118654752f));
            v2 = 0.5f * v2 * (1.0f + erff(v2 * 0.70710678118654752f));
            v3 = 0.5f * v3 * (1.0f + erff(v3 * 0.70710678118654752f));
            h1s[ty * 4 + i][tx * 4 + 0] = v0;
            h1s[ty * 4 + i][tx * 4 + 1] = v1;
            h1s[ty * 4 + i][tx * 4 + 2] = v2;
            h1s[ty * 4 + i][tx * 4 + 3] = v3;
        }
    }
    __syncthreads();

    // ---- Phase C: ang = tanh(h1 @ W2 + b2); sincos -> LDS; ang -> global ----
    const int cj = t & 63;               // col 0..63
    const int rg = t >> 6;               // rows rg*8..rg*8+7
    float acc2[8];
    #pragma unroll
    for (int i = 0; i < 8; ++i) acc2[i] = 0.f;

    for (int h = 0; h < 2; ++h) {
        __syncthreads();
        const float4* wg = (const float4*)(W2 + h * 64 * NB);
        float4* wl = (float4*)wt;
        #pragma unroll
        for (int m = 0; m < 4; ++m) wl[t + m * 256] = wg[t + m * 256];
        __syncthreads();
        #pragma unroll
        for (int kk = 0; kk < 64; kk += 4) {
            const float w0 = wt[(kk + 0) * 64 + cj];
            const float w1 = wt[(kk + 1) * 64 + cj];
            const float w2 = wt[(kk + 2) * 64 + cj];
            const float w3 = wt[(kk + 3) * 64 + cj];
            #pragma unroll
            for (int i = 0; i < 8; ++i) {
                float4 hb = *(const float4*)&h1s[rg * 8 + i][h * 64 + kk];
                acc2[i] += hb.x * w0 + hb.y * w1 + hb.z * w2 + hb.w * w3;
            }
        }
    }
    {
        const float bb = b2[cj];
        #pragma unroll
        for (int i = 0; i < 8; ++i) {
            const int r = rg * 8 + i;
            float a = tanhf(acc2[i] + bb);
            ang_out[(size_t)(n0 + r) * NB + cj] = a;
            float sv, cv;
            sincosf(a, &sv, &cv);
            csc[r][cj] = cv;
            css[r][cj] = sv;
        }
    }
    __syncthreads();

    // ---- Phase D: rotate fibers, segment-reduce into per-graph sums ----
    // channel c = 4*b + 2*i + f ; xrot[4b+f] = c*x0 - s*x1 ; xrot[4b+2+f] = s*x0 + c*x1
    {
        const int c = t;
        const int b = c >> 2;
        const int idx = c & 3;
        const int i2 = idx >> 1;
        const int f = idx & 1;
        float racc = 0.f;
        int rcnt = 0;
        int gprev = batch[n0];
        for (int r = 0; r < BLKN; ++r) {
            const int g = batch[n0 + r];
            if (g != gprev) {
                atomicAdd(&gsums[gprev * GS + c], racc);
                if (t == 0) atomicAdd(&gsums[gprev * GS + 256], (float)rcnt);
                racc = 0.f; rcnt = 0; gprev = g;
            }
            const float x0 = xs[r][4 * b + f];
            const float x1 = xs[r][4 * b + 2 + f];
            const float cb = csc[r][b];
            const float sb = css[r][b];
            const float xr = (i2 == 0) ? (cb * x0 - sb * x1) : (sb * x0 + cb * x1);
            racc += xr;
            rcnt++;
        }
        atomicAdd(&gsums[gprev * GS + c], racc);
        if (t == 0) atomicAdd(&gsums[gprev * GS + 256], (float)rcnt);
    }
}

// ---------------------------------------------------------------------------
// K2: hmean[g] = (gsum[g] @ lin_w) / cnt + lin_b   (0 if cnt == 0)
// ---------------------------------------------------------------------------
__global__ __launch_bounds__(256)
void k2_hmean(const float* __restrict__ gsums, const float* __restrict__ lin_w,
              const float* __restrict__ lin_b, float* __restrict__ hmean)
{
    __shared__ float gs[C];
    __shared__ float cnt_sh;
    const int g = blockIdx.x;
    const int t = threadIdx.x;
    gs[t] = gsums[g * GS + t];
    if (t == 0) cnt_sh = gsums[g * GS + 256];
    __syncthreads();
    float a0 = 0.f, a1 = 0.f, a2 = 0.f, a3 = 0.f;
    #pragma unroll 4
    for (int k = 0; k < C; k += 4) {
        a0 += gs[k + 0] * lin_w[(size_t)(k + 0) * C + t];
        a1 += gs[k + 1] * lin_w[(size_t)(k + 1) * C + t];
        a2 += gs[k + 2] * lin_w[(size_t)(k + 2) * C + t];
        a3 += gs[k + 3] * lin_w[(size_t)(k + 3) * C + t];
    }
    const float cnt = cnt_sh;
    const float out = (cnt > 0.f) ? ((a0 + a1 + a2 + a3) / cnt + lin_b[t]) : 0.f;
    hmean[g * C + t] = out;
}

// ---------------------------------------------------------------------------
// K3: out = x + R(ang)^T hmean[batch[n]]; accumulate BN partial sums.
// ---------------------------------------------------------------------------
__global__ __launch_bounds__(256, 4)
void k3_inverse_resid(const float* __restrict__ x,
                      const int* __restrict__ batch,
                      const float* __restrict__ ang,
                      const float* __restrict__ hmean,
                      float* __restrict__ out,
                      float* __restrict__ bnsum, float* __restrict__ bnsq)
{
    __shared__ float hmrow[C];
    const int t = threadIdx.x;
    const int n0 = blockIdx.x * BLKN;
    const int b = t >> 2;
    const int idx = t & 3;
    const int i2 = idx >> 1;
    const int f = idx & 1;
    float bs = 0.f, bq = 0.f;
    int curg = -1;
    for (int r = 0; r < BLKN; ++r) {
        const int n = n0 + r;
        const int g = batch[n];         // uniform across block
        if (g != curg) {
            __syncthreads();
            hmrow[t] = hmean[g * C + t];
            __syncthreads();
            curg = g;
        }
        const float a = ang[(size_t)n * NB + b];
        float sv, cv;
        sincosf(a, &sv, &cv);
        const float h0 = hmrow[4 * b + f];
        const float h1v = hmrow[4 * b + 2 + f];
        const float hinv = (i2 == 0) ? (cv * h0 + sv * h1v) : (-sv * h0 + cv * h1v);
        const float o = x[(size_t)n * C + t] + hinv;
        out[(size_t)n * C + t] = o;
        bs += o;
        bq += o * o;
    }
    atomicAdd(&bnsum[t], bs);
    atomicAdd(&bnsq[t], bq);
}

// ---------------------------------------------------------------------------
// K4: BatchNorm finalize, in place over d_out.
// ---------------------------------------------------------------------------
__global__ __launch_bounds__(256)
void k4_bn(float* __restrict__ out, const float* __restrict__ bnsum,
           const float* __restrict__ bnsq, const float* __restrict__ gamma,
           const float* __restrict__ beta)
{
    __shared__ float mul_s[C], add_s[C];
    const int t = threadIdx.x;
    {
        const float inv_n = 1.0f / (float)N_NODES;
        const float mu = bnsum[t] * inv_n;
        const float var = bnsq[t] * inv_n - mu * mu;
        const float inv = rsqrtf(var + BN_EPS);
        const float m = gamma[t] * inv;
        mul_s[t] = m;
        add_s[t] = beta[t] - mu * m;
    }
    __syncthreads();
    float4* o4 = (float4*)out;
    const size_t total = (size_t)N_NODES * C / 4;   // 6.4M float4
    for (size_t i = (size_t)blockIdx.x * 256 + t; i < total;
         i += (size_t)gridDim.x * 256) {
        float4 v = o4[i];
        const int c0 = ((int)(i & 63)) * 4;
        v.x = v.x * mul_s[c0 + 0] + add_s[c0 + 0];
        v.y = v.y * mul_s[c0 + 1] + add_s[c0 + 1];
        v.z = v.z * mul_s[c0 + 2] + add_s[c0 + 2];
        v.w = v.w * mul_s[c0 + 3] + add_s[c0 + 3];
        o4[i] = v;
    }
}

// ---------------------------------------------------------------------------
extern "C" void kernel_launch(void* const* d_in, const int* in_sizes, int n_in,
                              void* d_out, int out_size, void* d_ws, size_t ws_size,
                              hipStream_t stream)
{
    const float* x      = (const float*)d_in[0];
    // d_in[1] = edge_index (unused, num_gnn == 0)
    const int* batch    = (const int*)d_in[2];     // harness delivers integers as int32
    const float* W1     = (const float*)d_in[3];
    const float* b1     = (const float*)d_in[4];
    const float* W2     = (const float*)d_in[5];
    const float* b2     = (const float*)d_in[6];
    const float* lin_w  = (const float*)d_in[7];
    const float* lin_b  = (const float*)d_in[8];
    const float* gamma  = (const float*)d_in[9];
    const float* beta   = (const float*)d_in[10];

    float* ws    = (float*)d_ws;
    float* gsums = ws + OFF_GSUMS;
    float* bnsum = ws + OFF_BNSUM;
    float* bnsq  = ws + OFF_BNSQ;
    float* hmean = ws + OFF_HMEAN;
    float* ang   = ws + OFF_ANG;
    float* out   = (float*)d_out;

    hipMemsetAsync(gsums, 0, ZERO_FLOATS * sizeof(float), stream);

    k1_angles_rot_pool<<<N_NODES / BLKN, 256, 0, stream>>>(x, batch, W1, b1, W2, b2,
                                                           gsums, ang);
    k2_hmean<<<NG, 256, 0, stream>>>(gsums, lin_w, lin_b, hmean);
    k3_inverse_resid<<<N_NODES / BLKN, 256, 0, stream>>>(x, batch, ang, hmean, out,
                                                         bnsum, bnsq);
    k4_bn<<<2048, 256, 0, stream>>>(out, bnsum, bnsq, gamma, beta);
}

// Round 3
// 362.339 us; speedup vs baseline: 1.4443x; 1.4443x over previous
//
#include <hip/hip_runtime.h>
#include <hip/hip_bf16.h>
#include <math.h>

#define N_NODES 100000
#define C 256
#define NB 64
#define H1D 128
#define NG 128
#define GS 257            // gsums row stride: 256 channels + 1 count
#define BN_EPS 1e-5f

#define BLKN 64
#define NBLK1 ((N_NODES + BLKN - 1) / BLKN)   // 1563

// ws layout (float offsets)
#define OFF_GSUMS 0
#define OFF_BNSUM (NG * GS)              // 32896
#define OFF_BNSQ  (OFF_BNSUM + 256)      // 33152
#define ZERO_FLOATS (OFF_BNSQ + 256)     // 33408 floats zeroed each launch
#define OFF_HMEAN ZERO_FLOATS            // 33408
#define OFF_WT1   (OFF_HMEAN + NG * C)   // 66176 ; 128x264 bf16 = 16896 floats
#define OFF_WT2   (OFF_WT1 + 16896)      // 83072 ; 64x136 bf16 = 4352 floats
#define OFF_CS    (OFF_WT2 + 4352)       // 87424 ; N*64 bf16 = 3.2M floats
#define OFF_SN    (OFF_CS + N_NODES * NB / 2)

#define WT1_LD 264   // bf16 stride (256 + 8 pad, keeps 16B alignment + 2-way banks)
#define WT2_LD 136

typedef __attribute__((ext_vector_type(8))) short bf16x8;
typedef __attribute__((ext_vector_type(4))) float f32x4;

__device__ __forceinline__ float bf2f(__hip_bfloat16 h) { return __bfloat162float(h); }

// ---------------------------------------------------------------------------
// K0: transpose+convert weights to bf16 [out_ch][in_ch] layout for MFMA B-frags
// ---------------------------------------------------------------------------
__global__ __launch_bounds__(256)
void k0_prep(const float* __restrict__ W1, const float* __restrict__ W2,
             __hip_bfloat16* __restrict__ Wt1, __hip_bfloat16* __restrict__ Wt2)
{
    const int t0 = threadIdx.x + blockIdx.x * 256;
    const int stride = gridDim.x * 256;
    for (int i = t0; i < 128 * 256; i += stride) {
        int n = i >> 8, k = i & 255;
        Wt1[n * WT1_LD + k] = __float2bfloat16(W1[k * 128 + n]);
    }
    for (int i = t0; i < 64 * 128; i += stride) {
        int n = i >> 7, k = i & 127;
        Wt2[n * WT2_LD + k] = __float2bfloat16(W2[k * 64 + n]);
    }
}

// ---------------------------------------------------------------------------
// K1: 64-node tile. MFMA GEMM1 (bf16) -> GELU -> MFMA GEMM2 -> tanh -> sincos;
//     write cos/sin (bf16) to global; rotate fibers; segment-reduce pooled sums.
// ---------------------------------------------------------------------------
__global__ __launch_bounds__(256, 2)
void k1_angles_rot_pool(const float* __restrict__ x,
                        const int* __restrict__ batch,
                        const __hip_bfloat16* __restrict__ Wt1g,
                        const float* __restrict__ b1,
                        const __hip_bfloat16* __restrict__ Wt2g,
                        const float* __restrict__ b2,
                        float* __restrict__ gsums,
                        __hip_bfloat16* __restrict__ csg,
                        __hip_bfloat16* __restrict__ sng)
{
    __shared__ __hip_bfloat16 xs[BLKN][264];    // 33792 B (stride 264: 16B-aligned, 2-way banks)
    __shared__ __hip_bfloat16 h1s[BLKN][136];   // 17408 B
    __shared__ __hip_bfloat16 csb[BLKN][72];    // 9216 B
    __shared__ __hip_bfloat16 snb[BLKN][72];    // 9216 B   total 69632 B -> 2 blocks/CU

    const int t = threadIdx.x;
    const int w = t >> 6;                 // wave 0..3
    const int l = t & 63;
    const int lo = l & 15, quad = l >> 4;
    const int n0 = blockIdx.x * BLKN;
    const int nrem = min(BLKN, N_NODES - n0);

    // ---- Phase A: x fp32 -> bf16 LDS tile (zero-fill tail rows) ----
    #pragma unroll
    for (int m = 0; m < 16; ++m) {
        int idx = t + m * 256;
        int r = idx >> 6, c4 = (idx & 63) * 4;
        float4 v;
        if (n0 + r < N_NODES) v = *(const float4*)(x + (size_t)(n0 + r) * C + c4);
        else { v.x = v.y = v.z = v.w = 0.f; }
        __hip_bfloat16* p = &xs[r][c4];
        p[0] = __float2bfloat16(v.x); p[1] = __float2bfloat16(v.y);
        p[2] = __float2bfloat16(v.z); p[3] = __float2bfloat16(v.w);
    }

    // ---- Preload B-fragments (GEMM1: wave owns n-tiles 2w,2w+1; GEMM2: all) ----
    bf16x8 bfr[2][8];
    #pragma unroll
    for (int nt = 0; nt < 2; ++nt) {
        const short* base = (const short*)Wt1g + (w * 32 + nt * 16 + lo) * WT1_LD + quad * 8;
        #pragma unroll
        for (int k = 0; k < 8; ++k) bfr[nt][k] = *(const bf16x8*)(base + k * 32);
    }
    bf16x8 b2f[4][4];
    #pragma unroll
    for (int nt = 0; nt < 4; ++nt) {
        const short* base = (const short*)Wt2g + (nt * 16 + lo) * WT2_LD + quad * 8;
        #pragma unroll
        for (int k = 0; k < 4; ++k) b2f[nt][k] = *(const bf16x8*)(base + k * 32);
    }
    __syncthreads();

    // ---- GEMM1: h1 = x[64,256] @ W1[256,128], wave computes 4 Mtiles x 2 Ntiles ----
    f32x4 acc1[4][2];
    #pragma unroll
    for (int mt = 0; mt < 4; ++mt) { acc1[mt][0] = (f32x4)0.f; acc1[mt][1] = (f32x4)0.f; }
    #pragma unroll
    for (int mt = 0; mt < 4; ++mt) {
        #pragma unroll
        for (int k = 0; k < 8; ++k) {
            bf16x8 afr = *(const bf16x8*)&xs[mt * 16 + lo][k * 32 + quad * 8];
            acc1[mt][0] = __builtin_amdgcn_mfma_f32_16x16x32_bf16(afr, bfr[0][k], acc1[mt][0], 0, 0, 0);
            acc1[mt][1] = __builtin_amdgcn_mfma_f32_16x16x32_bf16(afr, bfr[1][k], acc1[mt][1], 0, 0, 0);
        }
    }
    // bias + exact GELU -> h1s (C layout: row = mt*16+quad*4+r, col = w*32+nt*16+lo)
    #pragma unroll
    for (int nt = 0; nt < 2; ++nt) {
        const float bb = b1[w * 32 + nt * 16 + lo];
        #pragma unroll
        for (int mt = 0; mt < 4; ++mt) {
            #pragma unroll
            for (int r = 0; r < 4; ++r) {
                float v = acc1[mt][nt][r] + bb;
                v = 0.5f * v * (1.0f + erff(v * 0.70710678118654752f));
                h1s[mt * 16 + quad * 4 + r][w * 32 + nt * 16 + lo] = __float2bfloat16(v);
            }
        }
    }
    __syncthreads();

    // ---- GEMM2: ang = h1[64,128] @ W2[128,64]; wave owns Mtile w, 4 Ntiles ----
    f32x4 acc2[4];
    #pragma unroll
    for (int nt = 0; nt < 4; ++nt) acc2[nt] = (f32x4)0.f;
    #pragma unroll
    for (int k = 0; k < 4; ++k) {
        bf16x8 afr = *(const bf16x8*)&h1s[w * 16 + lo][k * 32 + quad * 8];
        #pragma unroll
        for (int nt = 0; nt < 4; ++nt)
            acc2[nt] = __builtin_amdgcn_mfma_f32_16x16x32_bf16(afr, b2f[nt][k], acc2[nt], 0, 0, 0);
    }
    // tanh -> sincos -> LDS (bf16)
    #pragma unroll
    for (int nt = 0; nt < 4; ++nt) {
        const float bb = b2[nt * 16 + lo];
        #pragma unroll
        for (int r = 0; r < 4; ++r) {
            float a = tanhf(acc2[nt][r] + bb);
            float sv, cv;
            sincosf(a, &sv, &cv);
            int row = w * 16 + quad * 4 + r;
            csb[row][nt * 16 + lo] = __float2bfloat16(cv);
            snb[row][nt * 16 + lo] = __float2bfloat16(sv);
        }
    }
    __syncthreads();

    // ---- coalesced global write of cos/sin (bf16, 2 per dword) ----
    #pragma unroll
    for (int m = 0; m < 8; ++m) {
        int idx = t + m * 256;          // 0..2047 : 64 rows x 32 dwords
        int row = idx >> 5;
        int c2 = (idx & 31) * 2;
        if (n0 + row < N_NODES) {
            *(unsigned int*)(csg + (size_t)(n0 + row) * NB + c2) = *(const unsigned int*)&csb[row][c2];
            *(unsigned int*)(sng + (size_t)(n0 + row) * NB + c2) = *(const unsigned int*)&snb[row][c2];
        }
    }

    // ---- Phase D: rotate + segment-reduce pooled sums (thread = channel) ----
    {
        const int b = t >> 2;
        const int idx = t & 3;
        const int i2 = idx >> 1;
        const int f = idx & 1;
        float racc = 0.f;
        int rcnt = 0;
        int gprev = batch[n0];
        for (int r = 0; r < nrem; ++r) {
            const int g = batch[n0 + r];
            if (g != gprev) {
                atomicAdd(&gsums[gprev * GS + t], racc);
                if (t == 0) atomicAdd(&gsums[gprev * GS + 256], (float)rcnt);
                racc = 0.f; rcnt = 0; gprev = g;
            }
            const float x0 = bf2f(xs[r][4 * b + f]);
            const float x1 = bf2f(xs[r][4 * b + 2 + f]);
            const float cb = bf2f(csb[r][b]);
            const float sb = bf2f(snb[r][b]);
            const float xr = (i2 == 0) ? (cb * x0 - sb * x1) : (sb * x0 + cb * x1);
            racc += xr;
            rcnt++;
        }
        atomicAdd(&gsums[gprev * GS + t], racc);
        if (t == 0) atomicAdd(&gsums[gprev * GS + 256], (float)rcnt);
    }
}

// ---------------------------------------------------------------------------
// K2: hmean[g] = (gsum[g] @ lin_w) / cnt + lin_b   (0 if cnt == 0)
// ---------------------------------------------------------------------------
__global__ __launch_bounds__(256)
void k2_hmean(const float* __restrict__ gsums, const float* __restrict__ lin_w,
              const float* __restrict__ lin_b, float* __restrict__ hmean)
{
    __shared__ float gs[C];
    __shared__ float cnt_sh;
    const int g = blockIdx.x;
    const int t = threadIdx.x;
    gs[t] = gsums[g * GS + t];
    if (t == 0) cnt_sh = gsums[g * GS + 256];
    __syncthreads();
    float a0 = 0.f, a1 = 0.f, a2 = 0.f, a3 = 0.f;
    #pragma unroll 4
    for (int k = 0; k < C; k += 4) {
        a0 += gs[k + 0] * lin_w[(size_t)(k + 0) * C + t];
        a1 += gs[k + 1] * lin_w[(size_t)(k + 1) * C + t];
        a2 += gs[k + 2] * lin_w[(size_t)(k + 2) * C + t];
        a3 += gs[k + 3] * lin_w[(size_t)(k + 3) * C + t];
    }
    const float cnt = cnt_sh;
    hmean[g * C + t] = (cnt > 0.f) ? ((a0 + a1 + a2 + a3) / cnt + lin_b[t]) : 0.f;
}

// ---------------------------------------------------------------------------
// K3: out = x + R^T hmean[batch[n]] (cos/sin precomputed bf16); BN partials.
//     thread t: node-slot s = t>>6, bundle cg = t&63 (4 channels, float4).
// ---------------------------------------------------------------------------
__global__ __launch_bounds__(256, 4)
void k3_inverse_resid(const float* __restrict__ x,
                      const int* __restrict__ batch,
                      const __hip_bfloat16* __restrict__ csg,
                      const __hip_bfloat16* __restrict__ sng,
                      const float* __restrict__ hmean,
                      float* __restrict__ out,
                      float* __restrict__ bnsum, float* __restrict__ bnsq)
{
    __shared__ float rs[4][C];
    __shared__ float rq[4][C];
    const int t = threadIdx.x;
    const int s = t >> 6;
    const int cg = t & 63;
    float bs0 = 0.f, bs1 = 0.f, bs2 = 0.f, bs3 = 0.f;
    float bq0 = 0.f, bq1 = 0.f, bq2 = 0.f, bq3 = 0.f;

    for (int base = blockIdx.x * 4; base < N_NODES; base += gridDim.x * 4) {
        const int n = base + s;
        if (n < N_NODES) {
            const int g = batch[n];
            const float4 hm = *(const float4*)(hmean + (size_t)g * C + cg * 4);
            const float cv = bf2f(csg[(size_t)n * NB + cg]);
            const float sv = bf2f(sng[(size_t)n * NB + cg]);
            const float4 xv = *(const float4*)(x + (size_t)n * C + cg * 4);
            float4 o;
            o.x = xv.x + cv * hm.x + sv * hm.z;
            o.y = xv.y + cv * hm.y + sv * hm.w;
            o.z = xv.z - sv * hm.x + cv * hm.z;
            o.w = xv.w - sv * hm.y + cv * hm.w;
            *(float4*)(out + (size_t)n * C + cg * 4) = o;
            bs0 += o.x; bs1 += o.y; bs2 += o.z; bs3 += o.w;
            bq0 += o.x * o.x; bq1 += o.y * o.y; bq2 += o.z * o.z; bq3 += o.w * o.w;
        }
    }
    rs[s][cg * 4 + 0] = bs0; rs[s][cg * 4 + 1] = bs1;
    rs[s][cg * 4 + 2] = bs2; rs[s][cg * 4 + 3] = bs3;
    rq[s][cg * 4 + 0] = bq0; rq[s][cg * 4 + 1] = bq1;
    rq[s][cg * 4 + 2] = bq2; rq[s][cg * 4 + 3] = bq3;
    __syncthreads();
    // one atomic per channel per block
    atomicAdd(&bnsum[t], rs[0][t] + rs[1][t] + rs[2][t] + rs[3][t]);
    atomicAdd(&bnsq[t],  rq[0][t] + rq[1][t] + rq[2][t] + rq[3][t]);
}

// ---------------------------------------------------------------------------
// K4: BatchNorm finalize, in place over d_out.
// ---------------------------------------------------------------------------
__global__ __launch_bounds__(256)
void k4_bn(float* __restrict__ out, const float* __restrict__ bnsum,
           const float* __restrict__ bnsq, const float* __restrict__ gamma,
           const float* __restrict__ beta)
{
    __shared__ float mul_s[C], add_s[C];
    const int t = threadIdx.x;
    {
        const float inv_n = 1.0f / (float)N_NODES;
        const float mu = bnsum[t] * inv_n;
        const float var = bnsq[t] * inv_n - mu * mu;
        const float inv = rsqrtf(var + BN_EPS);
        const float m = gamma[t] * inv;
        mul_s[t] = m;
        add_s[t] = beta[t] - mu * m;
    }
    __syncthreads();
    float4* o4 = (float4*)out;
    const size_t total = (size_t)N_NODES * C / 4;
    for (size_t i = (size_t)blockIdx.x * 256 + t; i < total;
         i += (size_t)gridDim.x * 256) {
        float4 v = o4[i];
        const int c0 = ((int)(i & 63)) * 4;
        v.x = v.x * mul_s[c0 + 0] + add_s[c0 + 0];
        v.y = v.y * mul_s[c0 + 1] + add_s[c0 + 1];
        v.z = v.z * mul_s[c0 + 2] + add_s[c0 + 2];
        v.w = v.w * mul_s[c0 + 3] + add_s[c0 + 3];
        o4[i] = v;
    }
}

// ---------------------------------------------------------------------------
extern "C" void kernel_launch(void* const* d_in, const int* in_sizes, int n_in,
                              void* d_out, int out_size, void* d_ws, size_t ws_size,
                              hipStream_t stream)
{
    const float* x      = (const float*)d_in[0];
    // d_in[1] = edge_index (unused, num_gnn == 0)
    const int* batch    = (const int*)d_in[2];     // harness delivers integers as int32
    const float* W1     = (const float*)d_in[3];
    const float* b1     = (const float*)d_in[4];
    const float* W2     = (const float*)d_in[5];
    const float* b2     = (const float*)d_in[6];
    const float* lin_w  = (const float*)d_in[7];
    const float* lin_b  = (const float*)d_in[8];
    const float* gamma  = (const float*)d_in[9];
    const float* beta   = (const float*)d_in[10];

    float* ws    = (float*)d_ws;
    float* gsums = ws + OFF_GSUMS;
    float* bnsum = ws + OFF_BNSUM;
    float* bnsq  = ws + OFF_BNSQ;
    float* hmean = ws + OFF_HMEAN;
    __hip_bfloat16* Wt1 = (__hip_bfloat16*)(ws + OFF_WT1);
    __hip_bfloat16* Wt2 = (__hip_bfloat16*)(ws + OFF_WT2);
    __hip_bfloat16* csg = (__hip_bfloat16*)(ws + OFF_CS);
    __hip_bfloat16* sng = (__hip_bfloat16*)(ws + OFF_SN);
    float* out   = (float*)d_out;

    hipMemsetAsync(gsums, 0, ZERO_FLOATS * sizeof(float), stream);

    k0_prep<<<32, 256, 0, stream>>>(W1, W2, Wt1, Wt2);
    k1_angles_rot_pool<<<NBLK1, 256, 0, stream>>>(x, batch, Wt1, b1, Wt2, b2,
                                                  gsums, csg, sng);
    k2_hmean<<<NG, 256, 0, stream>>>(gsums, lin_w, lin_b, hmean);
    k3_inverse_resid<<<512, 256, 0, stream>>>(x, batch, csg, sng, hmean, out,
                                              bnsum, bnsq);
    k4_bn<<<2048, 256, 0, stream>>>(out, bnsum, bnsq, gamma, beta);
}